// Round 11
// baseline (332.852 us; speedup 1.0000x reference)
//
#include <hip/hip_runtime.h>
#include <hip/hip_bf16.h>
#include <string.h>

#define NN   4096
#define NE   32768
#define NB   32
#define BKT  64   // per-src edge bucket capacity (deg ~ Poisson(8); P(>64) ~ 1e-30)
#define MSG_CHUNK 8

typedef __attribute__((ext_vector_type(8))) short short8;
typedef __attribute__((ext_vector_type(4))) float f4;

__device__ __forceinline__ float sigf(float x) { return 1.0f / (1.0f + __expf(-x)); }
__device__ __forceinline__ short f2bf(float f) {
    __hip_bfloat16 h = __float2bfloat16(f);
    short s;
    memcpy(&s, &h, sizeof(short));
    return s;
}

// ---------------- k_prep: W2F repack | edge bucket | S2S transpose | pre-MLP -------
// All four block families independent (counters pre-zeroed by hipMemsetAsync):
//   blocks    0..191: enn_W2 -> W2F fragment-packed bf16 (MFMA-ready)
//   blocks 192..319: edge bucket CSR fill (atomics on memset-zeroed counters)
//   blocks 320..351: WihT/WhhT transpose for k_s2s_post
//   blocks 352..1375: pre-MLP (4 nodes per block) + zero agg0/1/2
__global__ __launch_bounds__(256) void k_prep(const float* __restrict__ x,
        const float* __restrict__ W0, const float* __restrict__ b0,
        const float* __restrict__ W1, const float* __restrict__ b1,
        const float* __restrict__ W2, const float* __restrict__ b2,
        const float* __restrict__ enn_W2, __hip_bfloat16* __restrict__ W2F,
        const int* __restrict__ eidx, const float* __restrict__ ea,
        const float* __restrict__ Wih, const float* __restrict__ Whh,
        float* __restrict__ WihT, float* __restrict__ WhhT,
        float* __restrict__ out, float* __restrict__ aggAll,
        int* cnt_src, int* cnt_dst, int* csr_dst, float* csr_ea) {
    int bid = blockIdx.x, t = threadIdx.x;
    if (bid < 192) {
        __shared__ __hip_bfloat16 tile[4096];
        size_t base = (size_t)bid * 4096;
        for (int i = t; i < 4096; i += 256) {
            int k = i >> 6, o = i & 63;
            int pos = ((o >> 4) << 10) | ((k >> 5) << 9) | (((k >> 3) & 3) << 7)
                    | ((o & 15) << 3) | (k & 7);
            tile[pos] = __float2bfloat16(enn_W2[base + i]);
        }
        __syncthreads();
        for (int i = t; i < 4096; i += 256) W2F[base + i] = tile[i];
    } else if (bid < 320) {
        int e = (bid - 192) * 256 + t;                 // 128*256 == NE exactly
        int s = eidx[e];
        int d = eidx[NE + e];
        int slot = atomicAdd(&cnt_src[s], 1);
        if (slot < BKT) {
            csr_dst[s * BKT + slot] = d;
            csr_ea[s * BKT + slot] = ea[e];
        }
        atomicAdd(&cnt_dst[d], 1);
    } else if (bid < 352) {
        int c0 = (bid - 320) * 8;
        for (int i = t; i < 1024; i += 256) {
            int c = c0 + (i >> 7), j = i & 127;
            WihT[(size_t)c * 128 + j] = Wih[(size_t)j * 256 + c];
        }
        for (int i = t; i < 512; i += 256) {
            int c = c0 + (i >> 6), j = i & 63;
            WhhT[(size_t)c * 64 + j] = Whh[(size_t)j * 256 + c];
        }
    } else {
        __shared__ float xr[4][128], ha[4][64], hb[4][64];
        int w = t >> 6, j = t & 63;
        int n = (bid - 352) * 4 + w;
        xr[w][j] = x[(size_t)n * 128 + j];
        xr[w][64 + j] = x[(size_t)n * 128 + 64 + j];
        aggAll[(size_t)n * 64 + j] = 0.f;                        // agg0
        aggAll[(size_t)NN * 64 + (size_t)n * 64 + j] = 0.f;      // agg1
        aggAll[(size_t)2 * NN * 64 + (size_t)n * 64 + j] = 0.f;  // agg2
        float s = b0[j];
        #pragma unroll 8
        for (int k = 0; k < 128; ++k) s = fmaf(xr[w][k], W0[k * 64 + j], s);
        ha[w][j] = fmaxf(s, 0.f);
        s = b1[j];
        #pragma unroll 8
        for (int k = 0; k < 64; ++k) s = fmaf(ha[w][k], W1[k * 64 + j], s);
        hb[w][j] = fmaxf(s, 0.f);
        s = b2[j];
        #pragma unroll 8
        for (int k = 0; k < 64; ++k) s = fmaf(hb[w][k], W2[k * 64 + j], s);
        out[(size_t)n * 64 + j] = fmaxf(s, 0.f);
    }
}

// ---------------- k_fused: half-g P-tile MFMA in LDS + message scatter (layer 0) ----
// Block = (8-node tile) x (g-chunk of 32). ntile = bid>>1, gc = bid&1. Grid 1024.
// LDS 38.4 KB -> 4 blocks/CU (16 waves/CU); atomics 2x/edge (partial g-sums).
__global__ __launch_bounds__(256, 4) void k_fused(const float* __restrict__ out,
        const __hip_bfloat16* __restrict__ W2F_l, const float* __restrict__ b2l,
        const float* __restrict__ W1l, const float* __restrict__ b1l,
        const int* __restrict__ cnt_src, const int* __restrict__ csr_dst,
        const float* __restrict__ csr_ea, float* __restrict__ agg) {
    __shared__ __hip_bfloat16 Pt[8 * 2048];           // 32 KB swizzled half-g P tile
    __shared__ float outs[8][68];                     // fp32 node tile (padded)
    __shared__ float wlds[4][MSG_CHUNK][32];          // 4 KB We1 buffers (wave-private)
    int t = threadIdx.x, wave = t >> 6, lane = t & 63;
    int laneM = lane & 15, quad = lane >> 4;
    int ntile = blockIdx.x >> 1, gc = blockIdx.x & 1;
    int n0 = ntile * 8;
    for (int i = t; i < 512; i += 256) outs[i >> 6][i & 63] = out[(size_t)n0 * 64 + i];
    __syncthreads();
    // A fragments (rows = 8 nodes, rows 8..15 duplicated; K = 64)
    short8 a0, a1;
    {
        const float* ar = &outs[laneM & 7][quad * 8];
        #pragma unroll
        for (int j = 0; j < 8; ++j) a0[j] = f2bf(ar[j]);
        const float* ar2 = &outs[laneM & 7][32 + quad * 8];
        #pragma unroll
        for (int j = 0; j < 8; ++j) a1[j] = f2bf(ar2[j]);
    }
    // BT (fp32, same summation order as proven); only gc==0 contributes it
    float btr[2] = {0.f, 0.f};
    if (gc == 0) {
        for (int k = 0; k < 64; ++k) {
            float bv = b2l[k * 64 + lane];
            #pragma unroll
            for (int u = 0; u < 2; ++u) btr[u] = fmaf(outs[wave * 2 + u][k], bv, btr[u]);
        }
    }
    // Phase 1: wave w owns gl in [8w, 8w+8) (octet c = wave), 4 adjacent pairs
    #pragma unroll
    for (int gp = 0; gp < 4; ++gp) {
        int glA = wave * 8 + gp * 2;                   // even local g
        int gA = gc * 32 + glA;
        const __hip_bfloat16* BgA = W2F_l + (size_t)gA * 4096;
        const __hip_bfloat16* BgB = BgA + 4096;
        int c = wave;                                  // glA>>3
        int p = gp;                                    // (glA>>1)&3
        char* wb = (char*)Pt + (quad << 14) + (c << 10) + (laneM << 4)
                 + (((p ^ quad) & 3) << 2);
        #pragma unroll
        for (int sub = 0; sub < 4; ++sub) {
            short8 bA0 = *(const short8*)(BgA + sub * 1024 + lane * 8);
            short8 bA1 = *(const short8*)(BgA + sub * 1024 + 512 + lane * 8);
            short8 bB0 = *(const short8*)(BgB + sub * 1024 + lane * 8);
            short8 bB1 = *(const short8*)(BgB + sub * 1024 + 512 + lane * 8);
            f4 accA = {0.f, 0.f, 0.f, 0.f}, accB = {0.f, 0.f, 0.f, 0.f};
            accA = __builtin_amdgcn_mfma_f32_16x16x32_bf16(a0, bA0, accA, 0, 0, 0);
            accA = __builtin_amdgcn_mfma_f32_16x16x32_bf16(a1, bA1, accA, 0, 0, 0);
            accB = __builtin_amdgcn_mfma_f32_16x16x32_bf16(a0, bB0, accB, 0, 0, 0);
            accB = __builtin_amdgcn_mfma_f32_16x16x32_bf16(a1, bB1, accB, 0, 0, 0);
            if (quad < 2) {                            // nodes = quad*4+r in 0..7
                char* wbs = wb + (sub << 8);           // o += 16 -> 256 B
                #pragma unroll
                for (int r = 0; r < 4; ++r) {
                    unsigned pk = (unsigned)(unsigned short)f2bf(accA[r])
                                | ((unsigned)(unsigned short)f2bf(accB[r]) << 16);
                    *(unsigned*)(wbs + (r << 12)) = pk;    // node stride 4096 B
                }
            }
        }
    }
    __syncthreads();
    // Phase 2: partial-g message scatter, 2 srcs per wave, one atomic per (edge, gc)
    float w1v = (lane < 32) ? W1l[gc * 32 + lane] : 0.f;
    float b1v = (lane < 32) ? b1l[gc * 32 + lane] : 0.f;
    for (int u = 0; u < 2; ++u) {
        int nloc = wave * 2 + u;
        int n = n0 + nloc;
        int deg = cnt_src[n];
        if (deg > BKT) deg = BKT;
        if (deg <= 0) continue;
        int wq = nloc >> 2;                            // writer quad (0 or 1)
        float preg[32];                                // P[n, gl 0..31, o=lane]
        const char* Pn = (const char*)Pt + (nloc << 12);
        #pragma unroll
        for (int c2 = 0; c2 < 4; ++c2) {
            uint4 vv = *(const uint4*)(Pn + (c2 << 10) + (lane << 4));
            unsigned d0 = vv.x, d1 = vv.y, d2 = vv.z, d3 = vv.w;
            if (wq & 1) { unsigned tt = d0; d0 = d1; d1 = tt; tt = d2; d2 = d3; d3 = tt; }
            union { unsigned u2; float f; } cv;
            cv.u2 = d0 << 16;          preg[c2 * 8 + 0] = cv.f;
            cv.u2 = d0 & 0xFFFF0000u;  preg[c2 * 8 + 1] = cv.f;
            cv.u2 = d1 << 16;          preg[c2 * 8 + 2] = cv.f;
            cv.u2 = d1 & 0xFFFF0000u;  preg[c2 * 8 + 3] = cv.f;
            cv.u2 = d2 << 16;          preg[c2 * 8 + 4] = cv.f;
            cv.u2 = d2 & 0xFFFF0000u;  preg[c2 * 8 + 5] = cv.f;
            cv.u2 = d3 << 16;          preg[c2 * 8 + 6] = cv.f;
            cv.u2 = d3 & 0xFFFF0000u;  preg[c2 * 8 + 7] = cv.f;
        }
        float bt = btr[u];                             // 0 unless gc==0
        const int* bdst = csr_dst + n * BKT;
        const float* bea = csr_ea + n * BKT;
        for (int c0 = 0; c0 < deg; c0 += MSG_CHUNK) {
            int cc = deg - c0;
            if (cc > MSG_CHUNK) cc = MSG_CHUNK;
            int dl = 0; float el = 0.f;
            if (lane < cc) { dl = bdst[c0 + lane]; el = bea[c0 + lane]; }
            for (int si = 0; si < cc; ++si) {
                float eav = __shfl(el, si, 64);
                if (lane < 32)
                    wlds[wave][si][lane] = fmaxf(fmaf(eav, w1v, b1v), 0.f);  // lane = gl
            }
            for (int i = 0; i < cc; ++i) {
                int dst = __shfl(dl, i, 64);
                const float* wr = wlds[wave][i];
                float acc0 = bt, acc1 = 0.f, acc2 = 0.f, acc3 = 0.f;
                #pragma unroll
                for (int g = 0; g < 32; g += 16) {
                    float4 w0 = *(const float4*)(wr + g);
                    float4 w1 = *(const float4*)(wr + g + 4);
                    float4 w2 = *(const float4*)(wr + g + 8);
                    float4 w3 = *(const float4*)(wr + g + 12);
                    acc0 = fmaf(w0.x, preg[g], acc0);
                    acc0 = fmaf(w0.y, preg[g + 1], acc0);
                    acc0 = fmaf(w0.z, preg[g + 2], acc0);
                    acc0 = fmaf(w0.w, preg[g + 3], acc0);
                    acc1 = fmaf(w1.x, preg[g + 4], acc1);
                    acc1 = fmaf(w1.y, preg[g + 5], acc1);
                    acc1 = fmaf(w1.z, preg[g + 6], acc1);
                    acc1 = fmaf(w1.w, preg[g + 7], acc1);
                    acc2 = fmaf(w2.x, preg[g + 8], acc2);
                    acc2 = fmaf(w2.y, preg[g + 9], acc2);
                    acc2 = fmaf(w2.z, preg[g + 10], acc2);
                    acc2 = fmaf(w2.w, preg[g + 11], acc2);
                    acc3 = fmaf(w3.x, preg[g + 12], acc3);
                    acc3 = fmaf(w3.y, preg[g + 13], acc3);
                    acc3 = fmaf(w3.z, preg[g + 14], acc3);
                    acc3 = fmaf(w3.w, preg[g + 15], acc3);
                }
                float acc = (acc0 + acc1) + (acc2 + acc3);
                atomicAdd(&agg[(size_t)dst * 64 + lane], acc);   // partial; /deg in GRU
            }
        }
    }
}

// ---------------- k_fgru: GRU(l-1) prologue + half-g MFMA+scatter (layer l) ---------
// Same geometry as k_fused. Both gc blocks redundantly compute GRU(l-1) for the
// tile's 8 nodes (deterministic FMA -> bit-identical outs); only gc==0 writes
// out_cur. agg_in is read-only (3-buffer scheme: no zeroing, no races). GRU math
// is operand-for-operand the proven k_gru code (2 nodes per wave).
__global__ __launch_bounds__(256, 4) void k_fgru(
        const float* __restrict__ out_prev, float* __restrict__ out_cur,
        const float* __restrict__ agg_in, const int* __restrict__ cnt_dst,
        const float* __restrict__ rootW, const float* __restrict__ convb,
        const float* __restrict__ gWih, const float* __restrict__ gWhh,
        const float* __restrict__ gbih, const float* __restrict__ gbhh,
        const __hip_bfloat16* __restrict__ W2F_l, const float* __restrict__ b2l,
        const float* __restrict__ W1l, const float* __restrict__ b1l,
        const int* __restrict__ cnt_src, const int* __restrict__ csr_dst,
        const float* __restrict__ csr_ea, float* __restrict__ agg_out) {
    __shared__ __hip_bfloat16 Pt[8 * 2048];           // 32 KB swizzled half-g P tile
    __shared__ float outs[8][68];                     // fp32 node tile (padded)
    __shared__ float wlds[4][MSG_CHUNK][32];          // 4 KB (GRU scL aliases this)
    int t = threadIdx.x, wave = t >> 6, lane = t & 63;
    int laneM = lane & 15, quad = lane >> 4;
    int ntile = blockIdx.x >> 1, gc = blockIdx.x & 1;
    int n0 = ntile * 8;
    int j = lane;
    // ---- GRU(l-1) for the tile's 8 nodes (same FMA order as proven k_gru) ----
    for (int i = t; i < 512; i += 256)
        outs[i >> 6][i & 63] = out_prev[(size_t)n0 * 64 + i];
    __syncthreads();
    float* scL = &wlds[0][0][0];                      // 512 floats (phase-2 unused yet)
    for (int u = 0; u < 2; ++u) {
        int nl = wave * 2 + u;
        int n = n0 + nl;
        int dg = cnt_dst[n];
        float invd = 1.0f / (float)(dg > 0 ? dg : 1);
        float av = agg_in[(size_t)n * 64 + j];
        float s = av * invd + convb[j];
        #pragma unroll 8
        for (int k = 0; k < 64; ++k) s = fmaf(outs[nl][k], rootW[k * 64 + j], s);
        scL[nl * 64 + j] = fmaxf(s, 0.f);
    }
    __syncthreads();
    float o_new[2];
    for (int u = 0; u < 2; ++u) {
        int nl = wave * 2 + u;
        float hj = outs[nl][j];
        float gir = gbih[j], giz = gbih[64 + j], gin = gbih[128 + j];
        float ghr = gbhh[j], ghz = gbhh[64 + j], ghn = gbhh[128 + j];
        #pragma unroll 4
        for (int k = 0; k < 64; ++k) {
            float c = scL[nl * 64 + k], h = outs[nl][k];
            gir = fmaf(c, gWih[k * 192 + j], gir);
            giz = fmaf(c, gWih[k * 192 + 64 + j], giz);
            gin = fmaf(c, gWih[k * 192 + 128 + j], gin);
            ghr = fmaf(h, gWhh[k * 192 + j], ghr);
            ghz = fmaf(h, gWhh[k * 192 + 64 + j], ghz);
            ghn = fmaf(h, gWhh[k * 192 + 128 + j], ghn);
        }
        float r = sigf(gir + ghr);
        float z = sigf(giz + ghz);
        float nn2 = tanhf(gin + r * ghn);
        o_new[u] = (1.f - z) * nn2 + z * hj;
    }
    __syncthreads();
    for (int u = 0; u < 2; ++u) outs[wave * 2 + u][j] = o_new[u];
    __syncthreads();
    if (gc == 0)
        for (int i = t; i < 512; i += 256)
            out_cur[(size_t)n0 * 64 + i] = outs[i >> 6][i & 63];
    // ---- identical half-g MFMA + scatter body (layer l) ----
    short8 a0, a1;
    {
        const float* ar = &outs[laneM & 7][quad * 8];
        #pragma unroll
        for (int q = 0; q < 8; ++q) a0[q] = f2bf(ar[q]);
        const float* ar2 = &outs[laneM & 7][32 + quad * 8];
        #pragma unroll
        for (int q = 0; q < 8; ++q) a1[q] = f2bf(ar2[q]);
    }
    float btr[2] = {0.f, 0.f};
    if (gc == 0) {
        for (int k = 0; k < 64; ++k) {
            float bv = b2l[k * 64 + lane];
            #pragma unroll
            for (int u = 0; u < 2; ++u) btr[u] = fmaf(outs[wave * 2 + u][k], bv, btr[u]);
        }
    }
    #pragma unroll
    for (int gp = 0; gp < 4; ++gp) {
        int glA = wave * 8 + gp * 2;
        int gA = gc * 32 + glA;
        const __hip_bfloat16* BgA = W2F_l + (size_t)gA * 4096;
        const __hip_bfloat16* BgB = BgA + 4096;
        int c = wave;
        int p = gp;
        char* wb = (char*)Pt + (quad << 14) + (c << 10) + (laneM << 4)
                 + (((p ^ quad) & 3) << 2);
        #pragma unroll
        for (int sub = 0; sub < 4; ++sub) {
            short8 bA0 = *(const short8*)(BgA + sub * 1024 + lane * 8);
            short8 bA1 = *(const short8*)(BgA + sub * 1024 + 512 + lane * 8);
            short8 bB0 = *(const short8*)(BgB + sub * 1024 + lane * 8);
            short8 bB1 = *(const short8*)(BgB + sub * 1024 + 512 + lane * 8);
            f4 accA = {0.f, 0.f, 0.f, 0.f}, accB = {0.f, 0.f, 0.f, 0.f};
            accA = __builtin_amdgcn_mfma_f32_16x16x32_bf16(a0, bA0, accA, 0, 0, 0);
            accA = __builtin_amdgcn_mfma_f32_16x16x32_bf16(a1, bA1, accA, 0, 0, 0);
            accB = __builtin_amdgcn_mfma_f32_16x16x32_bf16(a0, bB0, accB, 0, 0, 0);
            accB = __builtin_amdgcn_mfma_f32_16x16x32_bf16(a1, bB1, accB, 0, 0, 0);
            if (quad < 2) {
                char* wbs = wb + (sub << 8);
                #pragma unroll
                for (int r = 0; r < 4; ++r) {
                    unsigned pk = (unsigned)(unsigned short)f2bf(accA[r])
                                | ((unsigned)(unsigned short)f2bf(accB[r]) << 16);
                    *(unsigned*)(wbs + (r << 12)) = pk;
                }
            }
        }
    }
    __syncthreads();
    float w1v = (lane < 32) ? W1l[gc * 32 + lane] : 0.f;
    float b1v = (lane < 32) ? b1l[gc * 32 + lane] : 0.f;
    for (int u = 0; u < 2; ++u) {
        int nloc = wave * 2 + u;
        int n = n0 + nloc;
        int deg = cnt_src[n];
        if (deg > BKT) deg = BKT;
        if (deg <= 0) continue;
        int wq = nloc >> 2;
        float preg[32];
        const char* Pn = (const char*)Pt + (nloc << 12);
        #pragma unroll
        for (int c2 = 0; c2 < 4; ++c2) {
            uint4 vv = *(const uint4*)(Pn + (c2 << 10) + (lane << 4));
            unsigned d0 = vv.x, d1 = vv.y, d2 = vv.z, d3 = vv.w;
            if (wq & 1) { unsigned tt = d0; d0 = d1; d1 = tt; tt = d2; d2 = d3; d3 = tt; }
            union { unsigned u2; float f; } cv;
            cv.u2 = d0 << 16;          preg[c2 * 8 + 0] = cv.f;
            cv.u2 = d0 & 0xFFFF0000u;  preg[c2 * 8 + 1] = cv.f;
            cv.u2 = d1 << 16;          preg[c2 * 8 + 2] = cv.f;
            cv.u2 = d1 & 0xFFFF0000u;  preg[c2 * 8 + 3] = cv.f;
            cv.u2 = d2 << 16;          preg[c2 * 8 + 4] = cv.f;
            cv.u2 = d2 & 0xFFFF0000u;  preg[c2 * 8 + 5] = cv.f;
            cv.u2 = d3 << 16;          preg[c2 * 8 + 6] = cv.f;
            cv.u2 = d3 & 0xFFFF0000u;  preg[c2 * 8 + 7] = cv.f;
        }
        float bt = btr[u];
        const int* bdst = csr_dst + n * BKT;
        const float* bea = csr_ea + n * BKT;
        for (int c0 = 0; c0 < deg; c0 += MSG_CHUNK) {
            int cc = deg - c0;
            if (cc > MSG_CHUNK) cc = MSG_CHUNK;
            int dl = 0; float el = 0.f;
            if (lane < cc) { dl = bdst[c0 + lane]; el = bea[c0 + lane]; }
            for (int si = 0; si < cc; ++si) {
                float eav = __shfl(el, si, 64);
                if (lane < 32)
                    wlds[wave][si][lane] = fmaxf(fmaf(eav, w1v, b1v), 0.f);
            }
            for (int i = 0; i < cc; ++i) {
                int dst = __shfl(dl, i, 64);
                const float* wr = wlds[wave][i];
                float acc0 = bt, acc1 = 0.f, acc2 = 0.f, acc3 = 0.f;
                #pragma unroll
                for (int g = 0; g < 32; g += 16) {
                    float4 w0 = *(const float4*)(wr + g);
                    float4 w1 = *(const float4*)(wr + g + 4);
                    float4 w2 = *(const float4*)(wr + g + 8);
                    float4 w3 = *(const float4*)(wr + g + 12);
                    acc0 = fmaf(w0.x, preg[g], acc0);
                    acc0 = fmaf(w0.y, preg[g + 1], acc0);
                    acc0 = fmaf(w0.z, preg[g + 2], acc0);
                    acc0 = fmaf(w0.w, preg[g + 3], acc0);
                    acc1 = fmaf(w1.x, preg[g + 4], acc1);
                    acc1 = fmaf(w1.y, preg[g + 5], acc1);
                    acc1 = fmaf(w1.z, preg[g + 6], acc1);
                    acc1 = fmaf(w1.w, preg[g + 7], acc1);
                    acc2 = fmaf(w2.x, preg[g + 8], acc2);
                    acc2 = fmaf(w2.y, preg[g + 9], acc2);
                    acc2 = fmaf(w2.z, preg[g + 10], acc2);
                    acc2 = fmaf(w2.w, preg[g + 11], acc2);
                    acc3 = fmaf(w3.x, preg[g + 12], acc3);
                    acc3 = fmaf(w3.y, preg[g + 13], acc3);
                    acc3 = fmaf(w3.z, preg[g + 14], acc3);
                    acc3 = fmaf(w3.w, preg[g + 15], acc3);
                }
                float acc = (acc0 + acc1) + (acc2 + acc3);
                atomicAdd(&agg_out[(size_t)dst * 64 + lane], acc);
            }
        }
    }
}

// ---------------- k_gru: conv (+deg-normalize) + GRU (final layer) ------------------
__global__ __launch_bounds__(256) void k_gru(const float* __restrict__ out,
        float* __restrict__ agg, const int* __restrict__ cnt_dst,
        const float* __restrict__ rootW, const float* __restrict__ convb,
        const float* __restrict__ Wih, const float* __restrict__ Whh,
        const float* __restrict__ bih, const float* __restrict__ bhh,
        float* __restrict__ outn) {
    __shared__ float sh[4][64], sc[4][64];
    int t = threadIdx.x, w = t >> 6, j = t & 63;
    int n = blockIdx.x * 4 + w;
    float hj = out[(size_t)n * 64 + j];
    sh[w][j] = hj;
    int dg = cnt_dst[n];
    float invd = 1.0f / (float)(dg > 0 ? dg : 1);
    float av = agg[(size_t)n * 64 + j];
    __syncthreads();
    float s = av * invd + convb[j];
    #pragma unroll 8
    for (int k = 0; k < 64; ++k) s = fmaf(sh[w][k], rootW[k * 64 + j], s);
    float conv = fmaxf(s, 0.f);
    sc[w][j] = conv;
    __syncthreads();
    float gir = bih[j], giz = bih[64 + j], gin = bih[128 + j];
    float ghr = bhh[j], ghz = bhh[64 + j], ghn = bhh[128 + j];
    #pragma unroll 4
    for (int k = 0; k < 64; ++k) {
        float c = sc[w][k], h = sh[w][k];
        gir = fmaf(c, Wih[k * 192 + j], gir);
        giz = fmaf(c, Wih[k * 192 + 64 + j], giz);
        gin = fmaf(c, Wih[k * 192 + 128 + j], gin);
        ghr = fmaf(h, Whh[k * 192 + j], ghr);
        ghz = fmaf(h, Whh[k * 192 + 64 + j], ghz);
        ghn = fmaf(h, Whh[k * 192 + 128 + j], ghn);
    }
    float r = sigf(gir + ghr);
    float z = sigf(giz + ghz);
    float nn = tanhf(gin + r * ghn);
    outn[(size_t)n * 64 + j] = (1.f - z) * nn + z * hj;
}

// ---------------- Set2Set (3 steps) + post-MLP: burst-latency version ---------------
// Batch range via binary search over sorted batch_map. Identical to proven R10 kernel.
__global__ __launch_bounds__(256, 1) void k_s2s_post(const float* __restrict__ out,
        const int* __restrict__ bm,
        const float* __restrict__ WihT, const float* __restrict__ WhhT,
        const float* __restrict__ bih, const float* __restrict__ bhh,
        const float* __restrict__ pW0, const float* __restrict__ pb0,
        const float* __restrict__ pW1, const float* __restrict__ pb1,
        const float* __restrict__ pW2, const float* __restrict__ pb2,
        const float* __restrict__ pW3, const float* __restrict__ pb3,
        float* __restrict__ y) {
    __shared__ float cacheT[64 * 193];     // transposed node tile (49.4 KB)
    __shared__ float wpost[16448];         // pW0|pW1|pW2|pW3 (64.3 KB)
    __shared__ float qs[128];              // [0:64]=q(hh), [64:128]=r_read
    __shared__ float hh_l[64];
    __shared__ float gates_l[256];
    __shared__ float ebuf[1024];
    __shared__ float redw[4], redw2[4];
    __shared__ float redbuf[4][64];
    __shared__ float tmp64[64];
    int t = threadIdx.x, wave = t >> 6, lane = t & 63;
    int b = blockIdx.x;
    int s0, e0;
    {
        int lo = 0, hi = NN;
        while (lo < hi) { int mid = (lo + hi) >> 1; if (bm[mid] < b) lo = mid + 1; else hi = mid; }
        s0 = lo;
        hi = NN;
        while (lo < hi) { int mid = (lo + hi) >> 1; if (bm[mid] < b + 1) lo = mid + 1; else hi = mid; }
        e0 = lo;
    }
    int cnt = e0 - s0;
    if (cnt < 0) cnt = 0;
    if (cnt > 1024) cnt = 1024;
    int ccnt = cnt < 192 ? cnt : 192;
    int nf4 = ccnt * 16;
    const float4* out4 = (const float4*)(out + (size_t)s0 * 64);
    float4 stg[12];
    #pragma unroll
    for (int i = 0; i < 12; ++i) {
        int v = t + i * 256;
        if (v < nf4) stg[i] = out4[v];
    }
    #pragma unroll
    for (int i = 0; i < 12; ++i) {
        int v = t + i * 256;
        if (v < nf4) {
            int row = v >> 4, dq = v & 15;
            cacheT[(dq * 4 + 0) * 193 + row] = stg[i].x;
            cacheT[(dq * 4 + 1) * 193 + row] = stg[i].y;
            cacheT[(dq * 4 + 2) * 193 + row] = stg[i].z;
            cacheT[(dq * 4 + 3) * 193 + row] = stg[i].w;
        }
    }
    {
        float4* wp4 = (float4*)wpost;
        #pragma unroll
        for (int i = 0; i < 8; ++i) { int v = t + i * 256; wp4[v] = ((const float4*)pW0)[v]; }
        #pragma unroll
        for (int i = 0; i < 4; ++i) { int v = t + i * 256; wp4[2048 + v] = ((const float4*)pW1)[v]; }
        #pragma unroll
        for (int i = 0; i < 4; ++i) { int v = t + i * 256; wp4[3072 + v] = ((const float4*)pW2)[v]; }
        if (t < 16) wp4[4096 + t] = ((const float4*)pW3)[t];
    }
    const float4* wihT4 = (const float4*)(WihT + (size_t)t * 128);
    const float4* whhT4 = (const float4*)(WhhT + (size_t)t * 64);
    float bsum = bih[t] + bhh[t];
    float ccr = 0.f;
    if (t < 128) qs[t] = 0.f;
    if (t < 64) hh_l[t] = 0.f;
    __syncthreads();
    const float4* qs4 = (const float4*)qs;
    const float4* hh4 = (const float4*)hh_l;
    for (int step = 0; step < 3; ++step) {
        float g0 = bsum, g1 = 0.f, g2 = 0.f, g3 = 0.f;
        #pragma unroll
        for (int jq = 0; jq < 32; ++jq) {
            float4 w = wihT4[jq];
            float4 v = qs4[jq];
            g0 = fmaf(v.x, w.x, g0);
            g1 = fmaf(v.y, w.y, g1);
            g2 = fmaf(v.z, w.z, g2);
            g3 = fmaf(v.w, w.w, g3);
        }
        #pragma unroll
        for (int jq = 0; jq < 16; ++jq) {
            float4 w = whhT4[jq];
            float4 v = hh4[jq];
            g0 = fmaf(v.x, w.x, g0);
            g1 = fmaf(v.y, w.y, g1);
            g2 = fmaf(v.z, w.z, g2);
            g3 = fmaf(v.w, w.w, g3);
        }
        gates_l[t] = (g0 + g1) + (g2 + g3);
        __syncthreads();                                     // B1: gates ready
        if (t < 64) {
            float cn = sigf(gates_l[64 + t]) * ccr
                     + sigf(gates_l[t]) * tanhf(gates_l[128 + t]);
            ccr = cn;
            hh_l[t] = sigf(gates_l[192 + t]) * tanhf(cn);
        }
        __syncthreads();                                     // B2: hh ready
        for (int idx = t; idx < cnt; idx += 256) {
            float s0a = 0.f, s1a = 0.f, s2a = 0.f, s3a = 0.f;
            if (idx < 192) {
                #pragma unroll
                for (int dq = 0; dq < 16; ++dq) {
                    float4 h = hh4[dq];
                    s0a = fmaf(cacheT[(dq * 4 + 0) * 193 + idx], h.x, s0a);
                    s1a = fmaf(cacheT[(dq * 4 + 1) * 193 + idx], h.y, s1a);
                    s2a = fmaf(cacheT[(dq * 4 + 2) * 193 + idx], h.z, s2a);
                    s3a = fmaf(cacheT[(dq * 4 + 3) * 193 + idx], h.w, s3a);
                }
            } else {
                const float* row = out + (size_t)(s0 + idx) * 64;
                #pragma unroll
                for (int dq = 0; dq < 16; ++dq) {
                    float4 h = hh4[dq];
                    s0a = fmaf(row[dq * 4 + 0], h.x, s0a);
                    s1a = fmaf(row[dq * 4 + 1], h.y, s1a);
                    s2a = fmaf(row[dq * 4 + 2], h.z, s2a);
                    s3a = fmaf(row[dq * 4 + 3], h.w, s3a);
                }
            }
            ebuf[idx] = (s0a + s1a) + (s2a + s3a);
        }
        __syncthreads();                                     // B3: e ready
        float lm = -3.0e38f;
        for (int idx = t; idx < cnt; idx += 256) lm = fmaxf(lm, ebuf[idx]);
        #pragma unroll
        for (int off = 32; off > 0; off >>= 1) lm = fmaxf(lm, __shfl_xor(lm, off, 64));
        if (lane == 0) redw[wave] = lm;
        __syncthreads();                                     // B4: wave maxes
        float m = fmaxf(fmaxf(redw[0], redw[1]), fmaxf(redw[2], redw[3]));
        float ls = 0.f;
        for (int idx = t; idx < cnt; idx += 256) {
            float a = __expf(ebuf[idx] - m);
            ebuf[idx] = a;
            ls += a;
        }
        #pragma unroll
        for (int off = 32; off > 0; off >>= 1) ls += __shfl_xor(ls, off, 64);
        if (lane == 0) redw2[wave] = ls;
        __syncthreads();                                     // B5: a's + wave sums
        float ssum = (redw2[0] + redw2[1]) + (redw2[2] + redw2[3]);
        float inv = (cnt > 0) ? 1.f / ssum : 0.f;
        float r0 = 0.f;
        for (int row = wave; row < ccnt; row += 4)
            r0 = fmaf(ebuf[row], cacheT[lane * 193 + row], r0);
        for (int row = 192 + wave; row < cnt; row += 4)
            r0 = fmaf(ebuf[row], out[(size_t)(s0 + row) * 64 + lane], r0);
        redbuf[wave][lane] = r0;
        __syncthreads();                                     // B6: wave partials
        if (t < 64) {
            float s = ((redbuf[0][t] + redbuf[1][t]) + (redbuf[2][t] + redbuf[3][t]));
            qs[64 + t] = s * inv;
            qs[t] = hh_l[t];
        }
        __syncthreads();                                     // B7: qs ready
    }
    if (t < 64) {
        float s = pb0[t];
        #pragma unroll 4
        for (int k = 0; k < 128; ++k) s = fmaf(qs[k], wpost[k * 64 + t], s);
        tmp64[t] = fmaxf(s, 0.f);
    }
    __syncthreads();
    float h1v = 0.f;
    if (t < 64) {
        float s = pb1[t];
        #pragma unroll 4
        for (int k = 0; k < 64; ++k) s = fmaf(tmp64[k], wpost[8192 + k * 64 + t], s);
        h1v = fmaxf(s, 0.f);
    }
    __syncthreads();
    if (t < 64) tmp64[t] = h1v;
    __syncthreads();
    if (t < 64) {
        float s = pb2[t];
        #pragma unroll 4
        for (int k = 0; k < 64; ++k) s = fmaf(tmp64[k], wpost[12288 + k * 64 + t], s);
        gates_l[t] = fmaxf(s, 0.f) * wpost[16384 + t];
    }
    __syncthreads();
    if (t == 0) {
        float yy = pb3[0];
        for (int k = 0; k < 64; ++k) yy += gates_l[k];
        y[b] = yy;
    }
}

// ---------------- host ----------------

extern "C" void kernel_launch(void* const* d_in, const int* in_sizes, int n_in,
                              void* d_out, int out_size, void* d_ws, size_t ws_size,
                              hipStream_t stream) {
    const float* x         = (const float*)d_in[0];
    const float* edge_attr = (const float*)d_in[1];
    const int*   edge_idx  = (const int*)d_in[2];
    const int*   batch_map = (const int*)d_in[3];
    const float* pre_W0 = (const float*)d_in[4];
    const float* pre_b0 = (const float*)d_in[5];
    const float* pre_W1 = (const float*)d_in[6];
    const float* pre_b1 = (const float*)d_in[7];
    const float* pre_W2 = (const float*)d_in[8];
    const float* pre_b2 = (const float*)d_in[9];
    const float* enn_W1 = (const float*)d_in[10];
    const float* enn_b1 = (const float*)d_in[11];
    const float* enn_W2 = (const float*)d_in[12];
    const float* enn_b2 = (const float*)d_in[13];
    const float* root_W = (const float*)d_in[14];
    const float* conv_b = (const float*)d_in[15];
    const float* gru_Wih = (const float*)d_in[16];
    const float* gru_Whh = (const float*)d_in[17];
    const float* gru_bih = (const float*)d_in[18];
    const float* gru_bhh = (const float*)d_in[19];
    const float* s2s_Wih = (const float*)d_in[20];
    const float* s2s_Whh = (const float*)d_in[21];
    const float* s2s_bih = (const float*)d_in[22];
    const float* s2s_bhh = (const float*)d_in[23];
    const float* post_W0 = (const float*)d_in[24];
    const float* post_b0 = (const float*)d_in[25];
    const float* post_W1 = (const float*)d_in[26];
    const float* post_b1 = (const float*)d_in[27];
    const float* post_W2 = (const float*)d_in[28];
    const float* post_b2 = (const float*)d_in[29];
    const float* post_W3 = (const float*)d_in[30];
    const float* post_b3 = (const float*)d_in[31];
    float* yout = (float*)d_out;

    char* wp = (char*)d_ws;
    auto take = [&](size_t bytes) -> char* {
        char* r = wp;
        wp += (bytes + 255) & ~(size_t)255;
        return r;
    };
    float* outA = (float*)take((size_t)NN * 64 * 4);
    float* outB = (float*)take((size_t)NN * 64 * 4);
    float* aggP = (float*)take((size_t)3 * NN * 64 * 4);   // agg0 | agg1 | agg2
    __hip_bfloat16* W2F = (__hip_bfloat16*)take((size_t)3 * 64 * 4096 * 2);
    int* cnt_src  = (int*)take((size_t)NN * 4);       // contiguous with cnt_dst:
    int* cnt_dst  = (int*)take((size_t)NN * 4);       //   one 32 KB memset covers both
    int* csr_dst  = (int*)take((size_t)NN * BKT * 4);
    float* csr_ea = (float*)take((size_t)NN * BKT * 4);
    float* WihT   = (float*)take((size_t)256 * 128 * 4);
    float* WhhT   = (float*)take((size_t)256 * 64 * 4);
    float* agg0 = aggP;
    float* agg1 = aggP + (size_t)NN * 64;
    float* agg2 = aggP + (size_t)2 * NN * 64;

    hipMemsetAsync(cnt_src, 0, (size_t)2 * NN * 4, stream);   // cnt_src + cnt_dst

    k_prep<<<1376, 256, 0, stream>>>(x, pre_W0, pre_b0, pre_W1, pre_b1, pre_W2, pre_b2,
                                     enn_W2, W2F, edge_idx, edge_attr,
                                     s2s_Wih, s2s_Whh, WihT, WhhT,
                                     outA, aggP, cnt_src, cnt_dst, csr_dst, csr_ea);

    // F0: layer-0 P-MFMA + scatter -> agg0 (out0 = outA from k_prep)
    k_fused<<<NN / 8 * 2, 256, 0, stream>>>(outA, W2F,
                                            enn_b2, enn_W1, enn_b1,
                                            cnt_src, csr_dst, csr_ea, agg0);
    // F1: GRU(l=0) from (outA, agg0) -> out1 = outB; layer-1 scatter -> agg1
    k_fgru<<<NN / 8 * 2, 256, 0, stream>>>(outA, outB, agg0, cnt_dst,
        root_W, conv_b, gru_Wih, gru_Whh, gru_bih, gru_bhh,
        W2F + (size_t)1 * 64 * 4096, enn_b2 + 4096, enn_W1 + 64, enn_b1 + 64,
        cnt_src, csr_dst, csr_ea, agg1);
    // F2: GRU(l=1) from (outB, agg1) -> out2 = outA; layer-2 scatter -> agg2
    k_fgru<<<NN / 8 * 2, 256, 0, stream>>>(outB, outA, agg1, cnt_dst,
        root_W + 4096, conv_b + 64, gru_Wih + 64 * 192, gru_Whh + 64 * 192,
        gru_bih + 192, gru_bhh + 192,
        W2F + (size_t)2 * 64 * 4096, enn_b2 + 2 * 4096, enn_W1 + 128, enn_b1 + 128,
        cnt_src, csr_dst, csr_ea, agg2);
    // final GRU(l=2): (outA, agg2) -> outB
    k_gru<<<NN / 4, 256, 0, stream>>>(outA, agg2, cnt_dst, root_W + 2 * 4096,
                                      conv_b + 2 * 64, gru_Wih + 2 * 64 * 192,
                                      gru_Whh + 2 * 64 * 192, gru_bih + 2 * 192,
                                      gru_bhh + 2 * 192, outB);
    k_s2s_post<<<NB, 256, 0, stream>>>(outB, batch_map, WihT, WhhT, s2s_bih,
                                       s2s_bhh, post_W0, post_b0, post_W1, post_b1,
                                       post_W2, post_b2, post_W3, post_b3, yout);
}

// Round 12
// 311.236 us; speedup vs baseline: 1.0695x; 1.0695x over previous
//
#include <hip/hip_runtime.h>
#include <hip/hip_bf16.h>
#include <string.h>

#define NN   4096
#define NE   32768
#define NB   32
#define BKT  64   // per-src edge bucket capacity (deg ~ Poisson(8); P(>64) ~ 1e-30)
#define MSG_CHUNK 8

typedef __attribute__((ext_vector_type(8))) short short8;
typedef __attribute__((ext_vector_type(4))) float f4;

__device__ __forceinline__ float sigf(float x) { return 1.0f / (1.0f + __expf(-x)); }
__device__ __forceinline__ short f2bf(float f) {
    __hip_bfloat16 h = __float2bfloat16(f);
    short s;
    memcpy(&s, &h, sizeof(short));
    return s;
}

// ---------------- k_prep: W2F repack | edge bucket | S2S transpose | pre-MLP -------
// All four block families independent (counters pre-zeroed by hipMemsetAsync):
//   blocks    0..191: enn_W2 -> W2F fragment-packed bf16 (MFMA-ready)
//   blocks 192..319: edge bucket CSR fill (atomics on memset-zeroed counters)
//   blocks 320..351: WihT/WhhT transpose for k_s2s_post
//   blocks 352..1375: pre-MLP (4 nodes per block) + agg zero
__global__ __launch_bounds__(256) void k_prep(const float* __restrict__ x,
        const float* __restrict__ W0, const float* __restrict__ b0,
        const float* __restrict__ W1, const float* __restrict__ b1,
        const float* __restrict__ W2, const float* __restrict__ b2,
        const float* __restrict__ enn_W2, __hip_bfloat16* __restrict__ W2F,
        const int* __restrict__ eidx, const float* __restrict__ ea,
        const float* __restrict__ Wih, const float* __restrict__ Whh,
        float* __restrict__ WihT, float* __restrict__ WhhT,
        float* __restrict__ out, float* __restrict__ agg,
        int* cnt_src, int* cnt_dst, int* csr_dst, float* csr_ea) {
    int bid = blockIdx.x, t = threadIdx.x;
    if (bid < 192) {
        __shared__ __hip_bfloat16 tile[4096];
        size_t base = (size_t)bid * 4096;
        for (int i = t; i < 4096; i += 256) {
            int k = i >> 6, o = i & 63;
            int pos = ((o >> 4) << 10) | ((k >> 5) << 9) | (((k >> 3) & 3) << 7)
                    | ((o & 15) << 3) | (k & 7);
            tile[pos] = __float2bfloat16(enn_W2[base + i]);
        }
        __syncthreads();
        for (int i = t; i < 4096; i += 256) W2F[base + i] = tile[i];
    } else if (bid < 320) {
        int e = (bid - 192) * 256 + t;                 // 128*256 == NE exactly
        int s = eidx[e];
        int d = eidx[NE + e];
        int slot = atomicAdd(&cnt_src[s], 1);
        if (slot < BKT) {
            csr_dst[s * BKT + slot] = d;
            csr_ea[s * BKT + slot] = ea[e];
        }
        atomicAdd(&cnt_dst[d], 1);
    } else if (bid < 352) {
        int c0 = (bid - 320) * 8;
        for (int i = t; i < 1024; i += 256) {
            int c = c0 + (i >> 7), j = i & 127;
            WihT[(size_t)c * 128 + j] = Wih[(size_t)j * 256 + c];
        }
        for (int i = t; i < 512; i += 256) {
            int c = c0 + (i >> 6), j = i & 63;
            WhhT[(size_t)c * 64 + j] = Whh[(size_t)j * 256 + c];
        }
    } else {
        __shared__ float xr[4][128], ha[4][64], hb[4][64];
        int w = t >> 6, j = t & 63;
        int n = (bid - 352) * 4 + w;
        xr[w][j] = x[(size_t)n * 128 + j];
        xr[w][64 + j] = x[(size_t)n * 128 + 64 + j];
        agg[(size_t)n * 64 + j] = 0.f;
        float s = b0[j];
        #pragma unroll 8
        for (int k = 0; k < 128; ++k) s = fmaf(xr[w][k], W0[k * 64 + j], s);
        ha[w][j] = fmaxf(s, 0.f);
        s = b1[j];
        #pragma unroll 8
        for (int k = 0; k < 64; ++k) s = fmaf(ha[w][k], W1[k * 64 + j], s);
        hb[w][j] = fmaxf(s, 0.f);
        s = b2[j];
        #pragma unroll 8
        for (int k = 0; k < 64; ++k) s = fmaf(hb[w][k], W2[k * 64 + j], s);
        out[(size_t)n * 64 + j] = fmaxf(s, 0.f);
    }
}

// ---------------- k_fused: half-g P-tile MFMA in LDS + message scatter --------------
// Block = (8-node tile) x (g-chunk of 32). ntile = bid>>1, gc = bid&1. Grid 1024.
// LDS 38.4 KB -> 4 blocks/CU (16 waves/CU); atomics 2x/edge (partial g-sums).
__global__ __launch_bounds__(256, 4) void k_fused(const float* __restrict__ out,
        const __hip_bfloat16* __restrict__ W2F_l, const float* __restrict__ b2l,
        const float* __restrict__ W1l, const float* __restrict__ b1l,
        const int* __restrict__ cnt_src, const int* __restrict__ csr_dst,
        const float* __restrict__ csr_ea, float* __restrict__ agg) {
    __shared__ __hip_bfloat16 Pt[8 * 2048];           // 32 KB swizzled half-g P tile
    __shared__ float outs[8][68];                     // fp32 node tile (padded)
    __shared__ float wlds[4][MSG_CHUNK][32];          // 4 KB We1 buffers (wave-private)
    int t = threadIdx.x, wave = t >> 6, lane = t & 63;
    int laneM = lane & 15, quad = lane >> 4;
    int ntile = blockIdx.x >> 1, gc = blockIdx.x & 1;
    int n0 = ntile * 8;
    for (int i = t; i < 512; i += 256) outs[i >> 6][i & 63] = out[(size_t)n0 * 64 + i];
    __syncthreads();
    // A fragments (rows = 8 nodes, rows 8..15 duplicated; K = 64)
    short8 a0, a1;
    {
        const float* ar = &outs[laneM & 7][quad * 8];
        #pragma unroll
        for (int j = 0; j < 8; ++j) a0[j] = f2bf(ar[j]);
        const float* ar2 = &outs[laneM & 7][32 + quad * 8];
        #pragma unroll
        for (int j = 0; j < 8; ++j) a1[j] = f2bf(ar2[j]);
    }
    // BT (fp32, same summation order as proven); only gc==0 contributes it
    float btr[2] = {0.f, 0.f};
    if (gc == 0) {
        for (int k = 0; k < 64; ++k) {
            float bv = b2l[k * 64 + lane];
            #pragma unroll
            for (int u = 0; u < 2; ++u) btr[u] = fmaf(outs[wave * 2 + u][k], bv, btr[u]);
        }
    }
    // Phase 1: wave w owns gl in [8w, 8w+8) (octet c = wave), 4 adjacent pairs
    #pragma unroll
    for (int gp = 0; gp < 4; ++gp) {
        int glA = wave * 8 + gp * 2;                   // even local g
        int gA = gc * 32 + glA;
        const __hip_bfloat16* BgA = W2F_l + (size_t)gA * 4096;
        const __hip_bfloat16* BgB = BgA + 4096;
        int c = wave;                                  // glA>>3
        int p = gp;                                    // (glA>>1)&3
        char* wb = (char*)Pt + (quad << 14) + (c << 10) + (laneM << 4)
                 + (((p ^ quad) & 3) << 2);
        #pragma unroll
        for (int sub = 0; sub < 4; ++sub) {
            short8 bA0 = *(const short8*)(BgA + sub * 1024 + lane * 8);
            short8 bA1 = *(const short8*)(BgA + sub * 1024 + 512 + lane * 8);
            short8 bB0 = *(const short8*)(BgB + sub * 1024 + lane * 8);
            short8 bB1 = *(const short8*)(BgB + sub * 1024 + 512 + lane * 8);
            f4 accA = {0.f, 0.f, 0.f, 0.f}, accB = {0.f, 0.f, 0.f, 0.f};
            accA = __builtin_amdgcn_mfma_f32_16x16x32_bf16(a0, bA0, accA, 0, 0, 0);
            accA = __builtin_amdgcn_mfma_f32_16x16x32_bf16(a1, bA1, accA, 0, 0, 0);
            accB = __builtin_amdgcn_mfma_f32_16x16x32_bf16(a0, bB0, accB, 0, 0, 0);
            accB = __builtin_amdgcn_mfma_f32_16x16x32_bf16(a1, bB1, accB, 0, 0, 0);
            if (quad < 2) {                            // nodes = quad*4+r in 0..7
                char* wbs = wb + (sub << 8);           // o += 16 -> 256 B
                #pragma unroll
                for (int r = 0; r < 4; ++r) {
                    unsigned pk = (unsigned)(unsigned short)f2bf(accA[r])
                                | ((unsigned)(unsigned short)f2bf(accB[r]) << 16);
                    *(unsigned*)(wbs + (r << 12)) = pk;    // node stride 4096 B
                }
            }
        }
    }
    __syncthreads();
    // Phase 2: partial-g message scatter, 2 srcs per wave, one atomic per (edge, gc)
    float w1v = (lane < 32) ? W1l[gc * 32 + lane] : 0.f;
    float b1v = (lane < 32) ? b1l[gc * 32 + lane] : 0.f;
    for (int u = 0; u < 2; ++u) {
        int nloc = wave * 2 + u;
        int n = n0 + nloc;
        int deg = cnt_src[n];
        if (deg > BKT) deg = BKT;
        if (deg <= 0) continue;
        int wq = nloc >> 2;                            // writer quad (0 or 1)
        float preg[32];                                // P[n, gl 0..31, o=lane]
        const char* Pn = (const char*)Pt + (nloc << 12);
        #pragma unroll
        for (int c2 = 0; c2 < 4; ++c2) {
            uint4 vv = *(const uint4*)(Pn + (c2 << 10) + (lane << 4));
            unsigned d0 = vv.x, d1 = vv.y, d2 = vv.z, d3 = vv.w;
            if (wq & 1) { unsigned tt = d0; d0 = d1; d1 = tt; tt = d2; d2 = d3; d3 = tt; }
            union { unsigned u2; float f; } cv;
            cv.u2 = d0 << 16;          preg[c2 * 8 + 0] = cv.f;
            cv.u2 = d0 & 0xFFFF0000u;  preg[c2 * 8 + 1] = cv.f;
            cv.u2 = d1 << 16;          preg[c2 * 8 + 2] = cv.f;
            cv.u2 = d1 & 0xFFFF0000u;  preg[c2 * 8 + 3] = cv.f;
            cv.u2 = d2 << 16;          preg[c2 * 8 + 4] = cv.f;
            cv.u2 = d2 & 0xFFFF0000u;  preg[c2 * 8 + 5] = cv.f;
            cv.u2 = d3 << 16;          preg[c2 * 8 + 6] = cv.f;
            cv.u2 = d3 & 0xFFFF0000u;  preg[c2 * 8 + 7] = cv.f;
        }
        float bt = btr[u];                             // 0 unless gc==0
        const int* bdst = csr_dst + n * BKT;
        const float* bea = csr_ea + n * BKT;
        for (int c0 = 0; c0 < deg; c0 += MSG_CHUNK) {
            int cc = deg - c0;
            if (cc > MSG_CHUNK) cc = MSG_CHUNK;
            int dl = 0; float el = 0.f;
            if (lane < cc) { dl = bdst[c0 + lane]; el = bea[c0 + lane]; }
            for (int si = 0; si < cc; ++si) {
                float eav = __shfl(el, si, 64);
                if (lane < 32)
                    wlds[wave][si][lane] = fmaxf(fmaf(eav, w1v, b1v), 0.f);  // lane = gl
            }
            for (int i = 0; i < cc; ++i) {
                int dst = __shfl(dl, i, 64);
                const float* wr = wlds[wave][i];
                float acc0 = bt, acc1 = 0.f, acc2 = 0.f, acc3 = 0.f;
                #pragma unroll
                for (int g = 0; g < 32; g += 16) {
                    float4 w0 = *(const float4*)(wr + g);
                    float4 w1 = *(const float4*)(wr + g + 4);
                    float4 w2 = *(const float4*)(wr + g + 8);
                    float4 w3 = *(const float4*)(wr + g + 12);
                    acc0 = fmaf(w0.x, preg[g], acc0);
                    acc0 = fmaf(w0.y, preg[g + 1], acc0);
                    acc0 = fmaf(w0.z, preg[g + 2], acc0);
                    acc0 = fmaf(w0.w, preg[g + 3], acc0);
                    acc1 = fmaf(w1.x, preg[g + 4], acc1);
                    acc1 = fmaf(w1.y, preg[g + 5], acc1);
                    acc1 = fmaf(w1.z, preg[g + 6], acc1);
                    acc1 = fmaf(w1.w, preg[g + 7], acc1);
                    acc2 = fmaf(w2.x, preg[g + 8], acc2);
                    acc2 = fmaf(w2.y, preg[g + 9], acc2);
                    acc2 = fmaf(w2.z, preg[g + 10], acc2);
                    acc2 = fmaf(w2.w, preg[g + 11], acc2);
                    acc3 = fmaf(w3.x, preg[g + 12], acc3);
                    acc3 = fmaf(w3.y, preg[g + 13], acc3);
                    acc3 = fmaf(w3.z, preg[g + 14], acc3);
                    acc3 = fmaf(w3.w, preg[g + 15], acc3);
                }
                float acc = (acc0 + acc1) + (acc2 + acc3);
                atomicAdd(&agg[(size_t)dst * 64 + lane], acc);   // partial; /deg in GRU
            }
        }
    }
}

// ---------------- k_gru: conv (+deg-normalize) + GRU (+ agg re-zero) ----------------
__global__ __launch_bounds__(256) void k_gru(const float* __restrict__ out,
        float* __restrict__ agg, const int* __restrict__ cnt_dst,
        const float* __restrict__ rootW, const float* __restrict__ convb,
        const float* __restrict__ Wih, const float* __restrict__ Whh,
        const float* __restrict__ bih, const float* __restrict__ bhh,
        float* __restrict__ outn) {
    __shared__ float sh[4][64], sc[4][64];
    int t = threadIdx.x, w = t >> 6, j = t & 63;
    int n = blockIdx.x * 4 + w;
    float hj = out[(size_t)n * 64 + j];
    sh[w][j] = hj;
    int dg = cnt_dst[n];
    float invd = 1.0f / (float)(dg > 0 ? dg : 1);
    float av = agg[(size_t)n * 64 + j];
    agg[(size_t)n * 64 + j] = 0.f;          // pre-zero for next layer's atomics
    __syncthreads();
    float s = av * invd + convb[j];
    #pragma unroll 8
    for (int k = 0; k < 64; ++k) s = fmaf(sh[w][k], rootW[k * 64 + j], s);
    float conv = fmaxf(s, 0.f);
    sc[w][j] = conv;
    __syncthreads();
    float gir = bih[j], giz = bih[64 + j], gin = bih[128 + j];
    float ghr = bhh[j], ghz = bhh[64 + j], ghn = bhh[128 + j];
    #pragma unroll 4
    for (int k = 0; k < 64; ++k) {
        float c = sc[w][k], h = sh[w][k];
        gir = fmaf(c, Wih[k * 192 + j], gir);
        giz = fmaf(c, Wih[k * 192 + 64 + j], giz);
        gin = fmaf(c, Wih[k * 192 + 128 + j], gin);
        ghr = fmaf(h, Whh[k * 192 + j], ghr);
        ghz = fmaf(h, Whh[k * 192 + 64 + j], ghz);
        ghn = fmaf(h, Whh[k * 192 + 128 + j], ghn);
    }
    float r = sigf(gir + ghr);
    float z = sigf(giz + ghz);
    float nn = tanhf(gin + r * ghn);
    outn[(size_t)n * 64 + j] = (1.f - z) * nn + z * hj;
}

// ---------------- Set2Set (3 steps) + post-MLP: burst-latency version ---------------
// Batch range via binary search over sorted batch_map (replaces bstart/bend arrays
// and their init/atomic pass). Otherwise identical to the proven R6 kernel.
__global__ __launch_bounds__(256, 1) void k_s2s_post(const float* __restrict__ out,
        const int* __restrict__ bm,
        const float* __restrict__ WihT, const float* __restrict__ WhhT,
        const float* __restrict__ bih, const float* __restrict__ bhh,
        const float* __restrict__ pW0, const float* __restrict__ pb0,
        const float* __restrict__ pW1, const float* __restrict__ pb1,
        const float* __restrict__ pW2, const float* __restrict__ pb2,
        const float* __restrict__ pW3, const float* __restrict__ pb3,
        float* __restrict__ y) {
    __shared__ float cacheT[64 * 193];     // transposed node tile (49.4 KB)
    __shared__ float wpost[16448];         // pW0|pW1|pW2|pW3 (64.3 KB)
    __shared__ float qs[128];              // [0:64]=q(hh), [64:128]=r_read
    __shared__ float hh_l[64];
    __shared__ float gates_l[256];
    __shared__ float ebuf[1024];
    __shared__ float redw[4], redw2[4];
    __shared__ float redbuf[4][64];
    __shared__ float tmp64[64];
    int t = threadIdx.x, wave = t >> 6, lane = t & 63;
    int b = blockIdx.x;
    // lower_bound(bm, b) and lower_bound(bm, b+1) -- bm sorted, broadcast loads
    int s0, e0;
    {
        int lo = 0, hi = NN;
        while (lo < hi) { int mid = (lo + hi) >> 1; if (bm[mid] < b) lo = mid + 1; else hi = mid; }
        s0 = lo;
        hi = NN;
        while (lo < hi) { int mid = (lo + hi) >> 1; if (bm[mid] < b + 1) lo = mid + 1; else hi = mid; }
        e0 = lo;
    }
    int cnt = e0 - s0;
    if (cnt < 0) cnt = 0;
    if (cnt > 1024) cnt = 1024;
    int ccnt = cnt < 192 ? cnt : 192;
    // ---- burst 1: node tile (<=192 rows -> <=3072 float4, 12 guarded/thread) ----
    int nf4 = ccnt * 16;
    const float4* out4 = (const float4*)(out + (size_t)s0 * 64);
    float4 stg[12];
    #pragma unroll
    for (int i = 0; i < 12; ++i) {
        int v = t + i * 256;
        if (v < nf4) stg[i] = out4[v];
    }
    #pragma unroll
    for (int i = 0; i < 12; ++i) {
        int v = t + i * 256;
        if (v < nf4) {
            int row = v >> 4, dq = v & 15;
            cacheT[(dq * 4 + 0) * 193 + row] = stg[i].x;
            cacheT[(dq * 4 + 1) * 193 + row] = stg[i].y;
            cacheT[(dq * 4 + 2) * 193 + row] = stg[i].z;
            cacheT[(dq * 4 + 3) * 193 + row] = stg[i].w;
        }
    }
    // ---- burst 2: post-MLP weights -> LDS (4112 float4 total) ----
    {
        float4* wp4 = (float4*)wpost;
        #pragma unroll
        for (int i = 0; i < 8; ++i) { int v = t + i * 256; wp4[v] = ((const float4*)pW0)[v]; }
        #pragma unroll
        for (int i = 0; i < 4; ++i) { int v = t + i * 256; wp4[2048 + v] = ((const float4*)pW1)[v]; }
        #pragma unroll
        for (int i = 0; i < 4; ++i) { int v = t + i * 256; wp4[3072 + v] = ((const float4*)pW2)[v]; }
        if (t < 16) wp4[4096 + t] = ((const float4*)pW3)[t];
    }
    const float4* wihT4 = (const float4*)(WihT + (size_t)t * 128);
    const float4* whhT4 = (const float4*)(WhhT + (size_t)t * 64);
    float bsum = bih[t] + bhh[t];
    float ccr = 0.f;                       // cc for dim t (threads t<64 only)
    if (t < 128) qs[t] = 0.f;
    if (t < 64) hh_l[t] = 0.f;
    __syncthreads();
    const float4* qs4 = (const float4*)qs;
    const float4* hh4 = (const float4*)hh_l;
    for (int step = 0; step < 3; ++step) {
        float g0 = bsum, g1 = 0.f, g2 = 0.f, g3 = 0.f;
        #pragma unroll
        for (int jq = 0; jq < 32; ++jq) {
            float4 w = wihT4[jq];
            float4 v = qs4[jq];
            g0 = fmaf(v.x, w.x, g0);
            g1 = fmaf(v.y, w.y, g1);
            g2 = fmaf(v.z, w.z, g2);
            g3 = fmaf(v.w, w.w, g3);
        }
        #pragma unroll
        for (int jq = 0; jq < 16; ++jq) {
            float4 w = whhT4[jq];
            float4 v = hh4[jq];
            g0 = fmaf(v.x, w.x, g0);
            g1 = fmaf(v.y, w.y, g1);
            g2 = fmaf(v.z, w.z, g2);
            g3 = fmaf(v.w, w.w, g3);
        }
        gates_l[t] = (g0 + g1) + (g2 + g3);
        __syncthreads();                                     // B1: gates ready
        if (t < 64) {
            float cn = sigf(gates_l[64 + t]) * ccr
                     + sigf(gates_l[t]) * tanhf(gates_l[128 + t]);
            ccr = cn;
            hh_l[t] = sigf(gates_l[192 + t]) * tanhf(cn);
        }
        __syncthreads();                                     // B2: hh ready
        for (int idx = t; idx < cnt; idx += 256) {
            float s0a = 0.f, s1a = 0.f, s2a = 0.f, s3a = 0.f;
            if (idx < 192) {
                #pragma unroll
                for (int dq = 0; dq < 16; ++dq) {
                    float4 h = hh4[dq];
                    s0a = fmaf(cacheT[(dq * 4 + 0) * 193 + idx], h.x, s0a);
                    s1a = fmaf(cacheT[(dq * 4 + 1) * 193 + idx], h.y, s1a);
                    s2a = fmaf(cacheT[(dq * 4 + 2) * 193 + idx], h.z, s2a);
                    s3a = fmaf(cacheT[(dq * 4 + 3) * 193 + idx], h.w, s3a);
                }
            } else {
                const float* row = out + (size_t)(s0 + idx) * 64;
                #pragma unroll
                for (int dq = 0; dq < 16; ++dq) {
                    float4 h = hh4[dq];
                    s0a = fmaf(row[dq * 4 + 0], h.x, s0a);
                    s1a = fmaf(row[dq * 4 + 1], h.y, s1a);
                    s2a = fmaf(row[dq * 4 + 2], h.z, s2a);
                    s3a = fmaf(row[dq * 4 + 3], h.w, s3a);
                }
            }
            ebuf[idx] = (s0a + s1a) + (s2a + s3a);
        }
        __syncthreads();                                     // B3: e ready
        float lm = -3.0e38f;
        for (int idx = t; idx < cnt; idx += 256) lm = fmaxf(lm, ebuf[idx]);
        #pragma unroll
        for (int off = 32; off > 0; off >>= 1) lm = fmaxf(lm, __shfl_xor(lm, off, 64));
        if (lane == 0) redw[wave] = lm;
        __syncthreads();                                     // B4: wave maxes
        float m = fmaxf(fmaxf(redw[0], redw[1]), fmaxf(redw[2], redw[3]));
        float ls = 0.f;
        for (int idx = t; idx < cnt; idx += 256) {
            float a = __expf(ebuf[idx] - m);
            ebuf[idx] = a;
            ls += a;
        }
        #pragma unroll
        for (int off = 32; off > 0; off >>= 1) ls += __shfl_xor(ls, off, 64);
        if (lane == 0) redw2[wave] = ls;
        __syncthreads();                                     // B5: a's + wave sums
        float ssum = (redw2[0] + redw2[1]) + (redw2[2] + redw2[3]);
        float inv = (cnt > 0) ? 1.f / ssum : 0.f;
        float r0 = 0.f;
        for (int row = wave; row < ccnt; row += 4)
            r0 = fmaf(ebuf[row], cacheT[lane * 193 + row], r0);
        for (int row = 192 + wave; row < cnt; row += 4)
            r0 = fmaf(ebuf[row], out[(size_t)(s0 + row) * 64 + lane], r0);
        redbuf[wave][lane] = r0;
        __syncthreads();                                     // B6: wave partials
        if (t < 64) {
            float s = ((redbuf[0][t] + redbuf[1][t]) + (redbuf[2][t] + redbuf[3][t]));
            qs[64 + t] = s * inv;
            qs[t] = hh_l[t];
        }
        __syncthreads();                                     // B7: qs ready
    }
    if (t < 64) {
        float s = pb0[t];
        #pragma unroll 4
        for (int k = 0; k < 128; ++k) s = fmaf(qs[k], wpost[k * 64 + t], s);
        tmp64[t] = fmaxf(s, 0.f);
    }
    __syncthreads();
    float h1v = 0.f;
    if (t < 64) {
        float s = pb1[t];
        #pragma unroll 4
        for (int k = 0; k < 64; ++k) s = fmaf(tmp64[k], wpost[8192 + k * 64 + t], s);
        h1v = fmaxf(s, 0.f);
    }
    __syncthreads();
    if (t < 64) tmp64[t] = h1v;
    __syncthreads();
    if (t < 64) {
        float s = pb2[t];
        #pragma unroll 4
        for (int k = 0; k < 64; ++k) s = fmaf(tmp64[k], wpost[12288 + k * 64 + t], s);
        gates_l[t] = fmaxf(s, 0.f) * wpost[16384 + t];
    }
    __syncthreads();
    if (t == 0) {
        float yy = pb3[0];
        for (int k = 0; k < 64; ++k) yy += gates_l[k];
        y[b] = yy;
    }
}

// ---------------- host ----------------

extern "C" void kernel_launch(void* const* d_in, const int* in_sizes, int n_in,
                              void* d_out, int out_size, void* d_ws, size_t ws_size,
                              hipStream_t stream) {
    const float* x         = (const float*)d_in[0];
    const float* edge_attr = (const float*)d_in[1];
    const int*   edge_idx  = (const int*)d_in[2];
    const int*   batch_map = (const int*)d_in[3];
    const float* pre_W0 = (const float*)d_in[4];
    const float* pre_b0 = (const float*)d_in[5];
    const float* pre_W1 = (const float*)d_in[6];
    const float* pre_b1 = (const float*)d_in[7];
    const float* pre_W2 = (const float*)d_in[8];
    const float* pre_b2 = (const float*)d_in[9];
    const float* enn_W1 = (const float*)d_in[10];
    const float* enn_b1 = (const float*)d_in[11];
    const float* enn_W2 = (const float*)d_in[12];
    const float* enn_b2 = (const float*)d_in[13];
    const float* root_W = (const float*)d_in[14];
    const float* conv_b = (const float*)d_in[15];
    const float* gru_Wih = (const float*)d_in[16];
    const float* gru_Whh = (const float*)d_in[17];
    const float* gru_bih = (const float*)d_in[18];
    const float* gru_bhh = (const float*)d_in[19];
    const float* s2s_Wih = (const float*)d_in[20];
    const float* s2s_Whh = (const float*)d_in[21];
    const float* s2s_bih = (const float*)d_in[22];
    const float* s2s_bhh = (const float*)d_in[23];
    const float* post_W0 = (const float*)d_in[24];
    const float* post_b0 = (const float*)d_in[25];
    const float* post_W1 = (const float*)d_in[26];
    const float* post_b1 = (const float*)d_in[27];
    const float* post_W2 = (const float*)d_in[28];
    const float* post_b2 = (const float*)d_in[29];
    const float* post_W3 = (const float*)d_in[30];
    const float* post_b3 = (const float*)d_in[31];
    float* yout = (float*)d_out;

    char* wp = (char*)d_ws;
    auto take = [&](size_t bytes) -> char* {
        char* r = wp;
        wp += (bytes + 255) & ~(size_t)255;
        return r;
    };
    float* outA = (float*)take((size_t)NN * 64 * 4);
    float* outB = (float*)take((size_t)NN * 64 * 4);
    float* agg  = (float*)take((size_t)NN * 64 * 4);
    __hip_bfloat16* W2F = (__hip_bfloat16*)take((size_t)3 * 64 * 4096 * 2);
    int* cnt_src  = (int*)take((size_t)NN * 4);       // contiguous with cnt_dst:
    int* cnt_dst  = (int*)take((size_t)NN * 4);       //   one 32 KB memset covers both
    int* csr_dst  = (int*)take((size_t)NN * BKT * 4);
    float* csr_ea = (float*)take((size_t)NN * BKT * 4);
    float* WihT   = (float*)take((size_t)256 * 128 * 4);
    float* WhhT   = (float*)take((size_t)256 * 64 * 4);

    hipMemsetAsync(cnt_src, 0, (size_t)2 * NN * 4, stream);   // cnt_src + cnt_dst

    k_prep<<<1376, 256, 0, stream>>>(x, pre_W0, pre_b0, pre_W1, pre_b1, pre_W2, pre_b2,
                                     enn_W2, W2F, edge_idx, edge_attr,
                                     s2s_Wih, s2s_Whh, WihT, WhhT,
                                     outA, agg, cnt_src, cnt_dst, csr_dst, csr_ea);

    float* cur = outA;
    float* nxt = outB;
    for (int l = 0; l < 3; ++l) {
        k_fused<<<NN / 8 * 2, 256, 0, stream>>>(cur, W2F + (size_t)l * 64 * 4096,
                                                enn_b2 + (size_t)l * 4096,
                                                enn_W1 + l * 64, enn_b1 + l * 64,
                                                cnt_src, csr_dst, csr_ea, agg);
        k_gru<<<NN / 4, 256, 0, stream>>>(cur, agg, cnt_dst, root_W + l * 4096,
                                          conv_b + l * 64, gru_Wih + l * 64 * 192,
                                          gru_Whh + l * 64 * 192, gru_bih + l * 192,
                                          gru_bhh + l * 192, nxt);
        float* tmp = cur; cur = nxt; nxt = tmp;
    }
    k_s2s_post<<<NB, 256, 0, stream>>>(cur, batch_map, WihT, WhhT, s2s_bih,
                                       s2s_bhh, post_W0, post_b0, post_W1, post_b1,
                                       post_W2, post_b2, post_W3, post_b3, yout);
}